// Round 5
// baseline (164.271 us; speedup 1.0000x reference)
//
#include <hip/hip_runtime.h>
#include <hip/hip_bf16.h>
#include <stdint.h>

// Problem constants (from reference)
#define N_NODES_C 100000
#define N_EDGES_C 600000
#define H_C 128

// MFMA fragment types: 32x32x16 bf16 -> A/B = 8 bf16 (4 VGPR), C/D = 16 f32
typedef __bf16 bf16x8 __attribute__((ext_vector_type(8)));
typedef float f32x16 __attribute__((ext_vector_type(16)));
typedef _Float16 half8 __attribute__((ext_vector_type(8)));
typedef unsigned short ushort8 __attribute__((ext_vector_type(8)));

// fp32 -> bf16 round-to-nearest-even
__device__ __forceinline__ unsigned short f2bf(float f) {
    unsigned int u = __builtin_bit_cast(unsigned int, f);
    u += 0x7fffu + ((u >> 16) & 1u);
    return (unsigned short)(u >> 16);
}

// Kernel 1: W1 fp32 [256,128] -> bf16 combined-B in MFMA B-fragment order.
// Bc[k][n2], k=0..127, n2=0..255:  n2<128 -> W1[k][n2] (u path),
//                                  n2>=128 -> W1[128+k][n2-128] (v path).
// Fragment (s = K-step 0..7, T = N-subtile 0..7): lane L holds
// Bc[k = s*16 + (L>>5)*8 + j][n2 = T*32 + (L&31)], j = 0..7 contiguous.
// Flat index: ((s*8 + T)*64 + L)*8 + j   (32768 elements, 64 KB)
__global__ void w1fmt_kernel(const float* __restrict__ W1,
                             unsigned short* __restrict__ w1f) {
    int i = blockIdx.x * blockDim.x + threadIdx.x;
    if (i >= 8 * 8 * 64 * 8) return;
    int j = i & 7;
    int L = (i >> 3) & 63;
    int t = (i >> 9) & 7;
    int s = (i >> 12) & 7;
    int k  = s * 16 + ((L >> 5) * 8) + j;   // 0..127
    int n2 = t * 32 + (L & 31);             // 0..255
    float w = (n2 < 128) ? W1[k * H_C + n2]
                         : W1[(128 + k) * H_C + (n2 - 128)];
    w1f[i] = f2bf(w);
}

// Kernel 2 (v2): node GEMM. uv[0:N*128) = u' = z @ W1[:128] + b1 (fp16),
//                uv[N*128:) = v = z @ W1[128:] (fp16).
// Block = 4 waves; wave wv owns N-subtiles T = {2wv, 2wv+1} (N=64 slice) and
// holds its 16 B-fragments in REGISTERS for the whole kernel (primed once).
// Grid-stride over 32-node tiles; per tile: all 16 A float4 loads issued
// upfront (max MLP), then convert+MFMA, then fp16 pack/store epilogue.
__launch_bounds__(256, 2)
__global__ void node_gemm_kernel(const float* __restrict__ z,
                                 const unsigned short* __restrict__ w1f,
                                 const float* __restrict__ b1,
                                 _Float16* __restrict__ uv) {
    const int lane = threadIdx.x & 63;
    const int wv   = threadIdx.x >> 6;      // wave 0..3
    const int l31  = lane & 31;
    const int half = lane >> 5;
    const int uh   = wv >> 1;               // 0 = u half (b1), 1 = v half

    // Prime B fragments once: 8 K-steps x 2 N-subtiles = 16 x 16 B in VGPRs.
    bf16x8 bfrag[8][2];
    #pragma unroll
    for (int s = 0; s < 8; ++s) {
        #pragma unroll
        for (int t = 0; t < 2; ++t) {
            bfrag[s][t] = reinterpret_cast<const bf16x8*>(w1f)
                              [(s * 8 + wv * 2 + t) * 64 + lane];
        }
    }

    float badd[2];
    int   ncol[2];
    #pragma unroll
    for (int t = 0; t < 2; ++t) {
        int n2  = (wv * 2 + t) * 32 + l31;  // global column 0..255
        ncol[t] = n2 - uh * 128;            // column within u/v half
        badd[t] = uh ? 0.0f : b1[n2];
    }
    const size_t segbase = uh ? (size_t)N_NODES_C * H_C : 0;

    for (int tile = blockIdx.x; tile < N_NODES_C / 32; tile += gridDim.x) {
        const float* arow = z + (size_t)(tile * 32 + l31) * H_C + half * 8;

        // Issue ALL A-loads for this tile before any dependent use.
        float4 alo[8], ahi[8];
        #pragma unroll
        for (int s = 0; s < 8; ++s) {
            alo[s] = *reinterpret_cast<const float4*>(arow + s * 16);
            ahi[s] = *reinterpret_cast<const float4*>(arow + s * 16 + 4);
        }

        f32x16 acc[2] = {};
        #pragma unroll
        for (int s = 0; s < 8; ++s) {
            ushort8 au;
            au[0] = f2bf(alo[s].x); au[1] = f2bf(alo[s].y);
            au[2] = f2bf(alo[s].z); au[3] = f2bf(alo[s].w);
            au[4] = f2bf(ahi[s].x); au[5] = f2bf(ahi[s].y);
            au[6] = f2bf(ahi[s].z); au[7] = f2bf(ahi[s].w);
            bf16x8 a = __builtin_bit_cast(bf16x8, au);
            acc[0] = __builtin_amdgcn_mfma_f32_32x32x16_bf16(a, bfrag[s][0], acc[0], 0, 0, 0);
            acc[1] = __builtin_amdgcn_mfma_f32_32x32x16_bf16(a, bfrag[s][1], acc[1], 0, 0, 0);
        }

        // Epilogue: +b1 (u half), fp16 pack via lane-pair shuffle, dword store.
        const int node0 = tile * 32;
        #pragma unroll
        for (int t = 0; t < 2; ++t) {
            #pragma unroll
            for (int r = 0; r < 16; ++r) {
                int row = (r & 3) + 8 * (r >> 2) + 4 * half;    // C/D row map
                float v = acc[t][r] + badd[t];
                float fo = __shfl_xor(v, 1);
                if ((lane & 1) == 0) {
                    unsigned int pk = __builtin_bit_cast(
                        unsigned int, __builtin_amdgcn_cvt_pkrtz(v, fo));
                    size_t idx = segbase + (size_t)(node0 + row) * H_C + ncol[t];
                    *reinterpret_cast<unsigned int*>(uv + idx) = pk;
                }
            }
        }
    }
}

// Kernel 3: edge phase. Quarter-wave (16 lanes) per FOUR consecutive edges:
// indices via two broadcast int4 loads; 8 row-gathers (16 B/lane) in flight;
// per-edge dot with W2 slice; 4-step xor-shuffle reduce; lane 0 stores float4.
__global__ void edge_kernel(const _Float16* __restrict__ uv,
                            const int* __restrict__ ei,
                            const float* __restrict__ w2,
                            const float* __restrict__ b2,
                            float* __restrict__ out) {
    const int tid = blockIdx.x * blockDim.x + threadIdx.x;
    const int j   = tid & 15;                       // lane within quarter
    const int q   = tid >> 4;                       // quarter id
    const int e0  = q * 4;
    if (e0 >= N_EDGES_C) return;

    float w2v[8];
    {
        float4 a = *reinterpret_cast<const float4*>(w2 + j * 8);
        float4 b = *reinterpret_cast<const float4*>(w2 + j * 8 + 4);
        w2v[0] = a.x; w2v[1] = a.y; w2v[2] = a.z; w2v[3] = a.w;
        w2v[4] = b.x; w2v[5] = b.y; w2v[6] = b.z; w2v[7] = b.w;
    }
    const float c2 = b2[0];
    const _Float16* vbase = uv + (size_t)N_NODES_C * H_C;

    int4 ss = *reinterpret_cast<const int4*>(ei + e0);
    int4 dd = *reinterpret_cast<const int4*>(ei + N_EDGES_C + e0);

    half8 u0 = *reinterpret_cast<const half8*>(uv    + (size_t)ss.x * H_C + j * 8);
    half8 v0 = *reinterpret_cast<const half8*>(vbase + (size_t)dd.x * H_C + j * 8);
    half8 u1 = *reinterpret_cast<const half8*>(uv    + (size_t)ss.y * H_C + j * 8);
    half8 v1 = *reinterpret_cast<const half8*>(vbase + (size_t)dd.y * H_C + j * 8);
    half8 u2 = *reinterpret_cast<const half8*>(uv    + (size_t)ss.z * H_C + j * 8);
    half8 v2 = *reinterpret_cast<const half8*>(vbase + (size_t)dd.z * H_C + j * 8);
    half8 u3 = *reinterpret_cast<const half8*>(uv    + (size_t)ss.w * H_C + j * 8);
    half8 v3 = *reinterpret_cast<const half8*>(vbase + (size_t)dd.w * H_C + j * 8);

    float p0 = 0.0f, p1 = 0.0f, p2 = 0.0f, p3 = 0.0f;
    #pragma unroll
    for (int k = 0; k < 8; ++k) {
        float h0 = (float)u0[k] + (float)v0[k];
        float h1 = (float)u1[k] + (float)v1[k];
        float h2 = (float)u2[k] + (float)v2[k];
        float h3 = (float)u3[k] + (float)v3[k];
        h0 = h0 > 0.0f ? h0 : 0.0f;
        h1 = h1 > 0.0f ? h1 : 0.0f;
        h2 = h2 > 0.0f ? h2 : 0.0f;
        h3 = h3 > 0.0f ? h3 : 0.0f;
        p0 = fmaf(h0, w2v[k], p0);
        p1 = fmaf(h1, w2v[k], p1);
        p2 = fmaf(h2, w2v[k], p2);
        p3 = fmaf(h3, w2v[k], p3);
    }
    #pragma unroll
    for (int m = 1; m <= 8; m <<= 1) {
        p0 += __shfl_xor(p0, m);
        p1 += __shfl_xor(p1, m);
        p2 += __shfl_xor(p2, m);
        p3 += __shfl_xor(p3, m);
    }
    if (j == 0) {
        float4 o = { p0 + c2, p1 + c2, p2 + c2, p3 + c2 };
        *reinterpret_cast<float4*>(out + e0) = o;
    }
}

extern "C" void kernel_launch(void* const* d_in, const int* in_sizes, int n_in,
                              void* d_out, int out_size, void* d_ws, size_t ws_size,
                              hipStream_t stream) {
    const float* z  = (const float*)d_in[0];
    const int*   ei = (const int*)d_in[1];
    const float* W1 = (const float*)d_in[2];
    const float* b1 = (const float*)d_in[3];
    const float* W2 = (const float*)d_in[4];
    const float* b2 = (const float*)d_in[5];
    float* out = (float*)d_out;

    // Workspace: [w1f: 64 KB][uv: u' then v, 2 * 100000*128 fp16 = 51.2 MB]
    unsigned short* w1f = (unsigned short*)d_ws;
    _Float16* uv = (_Float16*)((char*)d_ws + 65536);

    w1fmt_kernel<<<(8 * 8 * 64 * 8 + 255) / 256, 256, 0, stream>>>(W1, w1f);

    // Grid-stride: 1024 blocks x 4 waves; each block covers ~3 node tiles,
    // B-fragments primed once per block.
    node_gemm_kernel<<<1024, 256, 0, stream>>>(z, w1f, b1, uv);

    int nquarters = N_EDGES_C / 4;       // 150000
    edge_kernel<<<(nquarters * 16 + 255) / 256, 256, 0, stream>>>(uv, ei, W2, b2, out);
}